// Round 1
// baseline (248.358 us; speedup 1.0000x reference)
//
#include <hip/hip_runtime.h>
#include <math.h>

// PlanningLoss: B=8192, S=6, H=48, W=80 masks.
// Strategy: gather only the mask windows each trajectory point touches
// (~26 MB logical vs 252 MB full read). One wave64 per (b,s).

#define MH 48
#define MW 80
#define TS 6   // trajectory steps

__global__ __launch_bounds__(256) void planning_partial(
    const float* __restrict__ pred,   // [B,6,2]
    const float* __restrict__ conf,   // [B,6]
    const float* __restrict__ targ,   // [B,6,2]
    const float* __restrict__ det,    // [B,48,80]
    const float* __restrict__ driv,   // [B,48,80]
    float* __restrict__ partials,     // [gridDim.x]
    int B)
{
    const int lane   = threadIdx.x & 63;
    const int widblk = threadIdx.x >> 6;          // wave id in block (0..3)
    const int gwid   = blockIdx.x * 4 + widblk;   // global wave id = b*6+s
    const int NW     = B * TS;

    float partial = 0.0f;

    if (gwid < NW) {
        const int b = gwid / TS;
        const int s = gwid - b * TS;

        // broadcast loads (all lanes same address -> 1 transaction)
        const float x = pred[(b * TS + s) * 2 + 0];
        const float y = pred[(b * TS + s) * 2 + 1];

        // pixel coords: match astype(int32) truncation + clip.
        // x / 0.5 == x*2 (exact); y / 0.625 kept as IEEE division.
        int px = (int)(x * 2.0f + 40.0f);
        int py = (int)(y / 0.625f + 24.0f);
        px = min(max(px, 0), MW - 1);
        py = min(max(py, 0), MH - 1);

        const size_t mbase = (size_t)b * (MH * MW);

        // ---- collision: max over det[py-5..py+5, px-4..px+4] (truncated) ----
        float m = -INFINITY;
        #pragma unroll
        for (int it = 0; it < 2; ++it) {
            int e = lane + it * 64;
            if (e < 99) {                 // 11 rows x 9 cols
                int r  = e / 9;
                int dy = r - 5;
                int dx = (e - r * 9) - 4;
                int yy = py + dy, xx = px + dx;
                if (yy >= 0 && yy < MH && xx >= 0 && xx < MW)
                    m = fmaxf(m, det[mbase + yy * MW + xx]);
            }
        }
        #pragma unroll
        for (int o = 32; o > 0; o >>= 1)
            m = fmaxf(m, __shfl_xor(m, o));

        // ---- lane compliance: mean over driv clamped 7x5 box ----
        float ssum = 0.0f;
        if (lane < 35) {                  // 7 rows x 5 cols
            int r  = lane / 5;
            int dy = r - 3;
            int dx = (lane - r * 5) - 2;
            int yy = py + dy, xx = px + dx;
            if (yy >= 0 && yy < MH && xx >= 0 && xx < MW)
                ssum = driv[mbase + yy * MW + xx];
        }
        #pragma unroll
        for (int o = 32; o > 0; o >>= 1)
            ssum += __shfl_xor(ssum, o);

        if (lane == 0) {
            int ymin = max(py - 3, 0), ymax = min(py + 4, MH);
            int xmin = max(px - 2, 0), xmax = min(px + 3, MW);
            float cnt  = (float)((ymax - ymin) * (xmax - xmin));
            float comp = ssum / cnt;      // exact sum of 0/1 -> exact mean

            // trajectory MSE term (this (b,s)'s two coords)
            float tx = x - targ[(b * TS + s) * 2 + 0];
            float ty = y - targ[(b * TS + s) * 2 + 1];
            float sq = tx * tx + ty * ty;

            // smoothness: ||(p[s+1]-p[s]) - (p[s]-p[s-1])||_2 for s in [1,4]
            float sm = 0.0f;
            if (s >= 1 && s <= TS - 2) {
                float xm = pred[(b * TS + s - 1) * 2 + 0];
                float ym = pred[(b * TS + s - 1) * 2 + 1];
                float xp = pred[(b * TS + s + 1) * 2 + 0];
                float yp = pred[(b * TS + s + 1) * 2 + 1];
                float ax = (xp - x) - (x - xm);
                float ay = (yp - y) - (y - ym);
                sm = sqrtf(ax * ax + ay * ay);
            }

            // confidence term
            float c  = conf[b * TS + s];
            float ce = c - (1.0f - m);
            ce = ce * ce;

            const float invBS = 1.0f / (float)NW;
            partial = sq * (1.0f * 0.5f * invBS)          // W_TRAJ / (B*S*2)
                    + m  * (5.0f * invBS)                 // W_COL  / (B*S)
                    + (1.0f - comp) * (2.0f * invBS)      // W_LANE / (B*S)
                    + sm * (0.5f / (float)(B * (TS - 2))) // W_SMOOTH / (B*(S-2))
                    + ce * (0.1f * invBS);                // W_CONF / (B*S)
        }
    }

    __shared__ float red[4];
    if (lane == 0) red[widblk] = partial;
    __syncthreads();
    if (threadIdx.x == 0)
        partials[blockIdx.x] = (red[0] + red[1]) + (red[2] + red[3]);
}

__global__ __launch_bounds__(256) void planning_reduce(
    const float* __restrict__ partials, int n, float* __restrict__ out)
{
    __shared__ float red[256];
    float s = 0.0f;
    for (int i = threadIdx.x; i < n; i += 256)
        s += partials[i];
    red[threadIdx.x] = s;
    __syncthreads();
    #pragma unroll
    for (int o = 128; o > 0; o >>= 1) {
        if (threadIdx.x < o) red[threadIdx.x] += red[threadIdx.x + o];
        __syncthreads();
    }
    if (threadIdx.x == 0) out[0] = red[0];
}

extern "C" void kernel_launch(void* const* d_in, const int* in_sizes, int n_in,
                              void* d_out, int out_size, void* d_ws, size_t ws_size,
                              hipStream_t stream) {
    const float* pred = (const float*)d_in[0];
    const float* conf = (const float*)d_in[1];
    const float* targ = (const float*)d_in[2];
    const float* det  = (const float*)d_in[3];
    const float* driv = (const float*)d_in[4];

    const int B    = in_sizes[3] / (MH * MW);
    const int nw   = B * TS;                 // one wave per (b,s)
    const int nblk = (nw + 3) / 4;           // 4 waves (256 threads) per block

    float* partials = (float*)d_ws;          // nblk floats of scratch

    planning_partial<<<nblk, 256, 0, stream>>>(pred, conf, targ, det, driv,
                                               partials, B);
    planning_reduce<<<1, 256, 0, stream>>>(partials, nblk, (float*)d_out);
}

// Round 3
// 238.413 us; speedup vs baseline: 1.0417x; 1.0417x over previous
//
#include <hip/hip_runtime.h>
#include <math.h>

// PlanningLoss: B=8192, S=6, masks [B,48,80].
// One wave64 per batch element b: all 6 points' mask windows gathered with
// 21 independent load instructions (max MLP, same-b L1 locality), then
// butterfly reductions. ~70 MB gathered vs 252 MB full read.

#define MH 48
#define MW 80
#define TS 6

__global__ __launch_bounds__(256) void planning_partial(
    const float* __restrict__ pred,   // [B,6,2]
    const float* __restrict__ conf,   // [B,6]
    const float* __restrict__ targ,   // [B,6,2]
    const float* __restrict__ det,    // [B,48,80]
    const float* __restrict__ driv,   // [B,48,80]
    float* __restrict__ partials,     // [gridDim.x]
    int B)
{
    const int lane = threadIdx.x & 63;
    const int wid  = threadIdx.x >> 6;           // wave in block (0..3)
    const int b    = blockIdx.x * 4 + wid;

    float partial = 0.0f;

    if (b < B) {
        // coalesced per-b loads (12 / 12 / 6 contiguous floats)
        const float pv = (lane < 12) ? pred[b * 12 + lane] : 0.0f;
        const float tv = (lane < 12) ? targ[b * 12 + lane] : 0.0f;
        const float cv = (lane < 6)  ? conf[b * 6 + lane]  : 0.0f;

        // broadcast raw coords + pixel coords for all 6 points (unrolled -> regs)
        float xs[TS], ys[TS];
        int   px[TS], py[TS];
        #pragma unroll
        for (int s = 0; s < TS; ++s) {
            xs[s] = __shfl(pv, 2 * s);
            ys[s] = __shfl(pv, 2 * s + 1);
            // match astype(int32) trunc + clip; /0.5 == *2 exact, /0.625 IEEE
            int ix = (int)(xs[s] * 2.0f + 40.0f);
            int iy = (int)(ys[s] / 0.625f + 24.0f);
            px[s] = min(max(ix, 0), MW - 1);
            py[s] = min(max(iy, 0), MH - 1);
        }

        const float* img = det  + (size_t)b * (MH * MW);
        const float* drv = driv + (size_t)b * (MH * MW);

        // issue ALL gathers before any reduction (18 independent loads)
        float mA[TS], mB[TS], dv[TS];
        #pragma unroll
        for (int s = 0; s < TS; ++s) {
            // det pass A: elements 0..63 of the 11x9 window (row = e/9)
            {
                int e = lane, r = e / 9;
                int yy = py[s] + r - 5, xx = px[s] + (e - 9 * r) - 4;
                mA[s] = (yy >= 0 && yy < MH && xx >= 0 && xx < MW)
                      ? img[yy * MW + xx] : -INFINITY;
            }
            // det pass B: elements 35..98 (overlap with A harmless under max)
            {
                int e = lane + 35, r = e / 9;
                int yy = py[s] + r - 5, xx = px[s] + (e - 9 * r) - 4;
                mB[s] = (yy >= 0 && yy < MH && xx >= 0 && xx < MW)
                      ? img[yy * MW + xx] : -INFINITY;
            }
            // driv: 7x5 window, 35 elements
            {
                int e = lane, r = e / 5;
                int yy = py[s] + r - 3, xx = px[s] + (e - 5 * r) - 2;
                dv[s] = (lane < 35 && yy >= 0 && yy < MH && xx >= 0 && xx < MW)
                      ? drv[yy * MW + xx] : 0.0f;
            }
        }

        // butterfly reductions: per-point max (collision) and sum (lane box)
        float col[TS], lsum[TS];
        #pragma unroll
        for (int s = 0; s < TS; ++s) {
            float m = fmaxf(mA[s], mB[s]);
            float d = dv[s];
            #pragma unroll
            for (int o = 32; o > 0; o >>= 1) {
                m = fmaxf(m, __shfl_xor(m, o));
                d += __shfl_xor(d, o);
            }
            col[s]  = m;
            lsum[s] = d;
        }

        // trajectory MSE for this b (12 coords, lanes >=12 contribute 0)
        float diff = pv - tv;
        float sq = diff * diff;
        #pragma unroll
        for (int o = 32; o > 0; o >>= 1) sq += __shfl_xor(sq, o);

        // wave-uniform epilogue (same arithmetic as round 1 per point)
        float colsum = 0.0f, ce = 0.0f, lanec = 0.0f;
        #pragma unroll
        for (int s = 0; s < TS; ++s) {
            colsum += col[s];
            float c = __shfl(cv, s);
            float e = c - (1.0f - col[s]);
            ce += e * e;
            int ymin = max(py[s] - 3, 0), ymax = min(py[s] + 4, MH);
            int xmin = max(px[s] - 2, 0), xmax = min(px[s] + 3, MW);
            lanec += 1.0f - lsum[s] / (float)((ymax - ymin) * (xmax - xmin));
        }
        // smoothness: ||(p[s+1]-p[s]) - (p[s]-p[s-1])|| for s=1..4
        float sm = 0.0f;
        #pragma unroll
        for (int s = 1; s <= TS - 2; ++s) {
            float ax = (xs[s + 1] - xs[s]) - (xs[s] - xs[s - 1]);
            float ay = (ys[s + 1] - ys[s]) - (ys[s] - ys[s - 1]);
            sm += sqrtf(ax * ax + ay * ay);
        }

        const float invBS = 1.0f / (float)(B * TS);
        partial = sq     * (1.0f * 0.5f * invBS)           // W_TRAJ / (B*S*2)
                + colsum * (5.0f * invBS)                   // W_COL  / (B*S)
                + lanec  * (2.0f * invBS)                   // W_LANE / (B*S)
                + sm     * (0.5f / (float)(B * (TS - 2)))   // W_SMOOTH / (B*4)
                + ce     * (0.1f * invBS);                  // W_CONF / (B*S)
    }

    __shared__ float red[4];
    if (lane == 0) red[wid] = partial;
    __syncthreads();
    if (threadIdx.x == 0)
        partials[blockIdx.x] = (red[0] + red[1]) + (red[2] + red[3]);
}

__global__ __launch_bounds__(256) void planning_reduce(
    const float* __restrict__ partials, int n, float* __restrict__ out)
{
    __shared__ float red[256];
    float s = 0.0f;
    for (int i = threadIdx.x; i < n; i += 256)
        s += partials[i];
    red[threadIdx.x] = s;
    __syncthreads();
    #pragma unroll
    for (int o = 128; o > 0; o >>= 1) {
        if (threadIdx.x < o) red[threadIdx.x] += red[threadIdx.x + o];
        __syncthreads();
    }
    if (threadIdx.x == 0) out[0] = red[0];
}

extern "C" void kernel_launch(void* const* d_in, const int* in_sizes, int n_in,
                              void* d_out, int out_size, void* d_ws, size_t ws_size,
                              hipStream_t stream) {
    const float* pred = (const float*)d_in[0];
    const float* conf = (const float*)d_in[1];
    const float* targ = (const float*)d_in[2];
    const float* det  = (const float*)d_in[3];
    const float* driv = (const float*)d_in[4];

    const int B    = in_sizes[3] / (MH * MW);
    const int nblk = (B + 3) / 4;            // one wave per b, 4 waves/block

    float* partials = (float*)d_ws;

    planning_partial<<<nblk, 256, 0, stream>>>(pred, conf, targ, det, driv,
                                               partials, B);
    planning_reduce<<<1, 256, 0, stream>>>(partials, nblk, (float*)d_out);
}